// Round 11
// baseline (323.174 us; speedup 1.0000x reference)
//
#include <hip/hip_runtime.h>
#include <hip/hip_bf16.h>

// GPT3 attention block, B=2 S=2048 D=2048 H=16 Dh=128.
// 8-phase 128x128 counted-vmcnt GEMM (2 blocks/CU) + swapped-QK^T 32x32
// flash attention with K-tile double-buffer (counted vmcnt, no full drain).

typedef __bf16 bf16x8 __attribute__((ext_vector_type(8)));
typedef float f32x4 __attribute__((ext_vector_type(4)));
typedef float f32x16 __attribute__((ext_vector_type(16)));
typedef unsigned short u16;
typedef unsigned int u32;

#define DEV static __device__ __forceinline__

DEV void gload_lds16(const void* g, void* l) {
  __builtin_amdgcn_global_load_lds(
      (const __attribute__((address_space(1))) void*)g,
      (__attribute__((address_space(3))) void*)l, 16, 0, 0);
}

DEV f32x4 mfma16(bf16x8 a, bf16x8 b, f32x4 c) {
  return __builtin_amdgcn_mfma_f32_16x16x32_bf16(a, b, c, 0, 0, 0);
}

DEV f32x16 mfma32(bf16x8 a, bf16x8 b, f32x16 c) {
  return __builtin_amdgcn_mfma_f32_32x32x16_bf16(a, b, c, 0, 0, 0);
}

DEV u16 f2bf(float x) {
  return __builtin_bit_cast(u16, __float2bfloat16(x));
}

DEV u32 pack2(float lo, float hi_) {
  return (u32)f2bf(lo) | ((u32)f2bf(hi_) << 16);
}

#define BAR() __builtin_amdgcn_s_barrier()

// ---------------- fp32 -> bf16 conversion ----------------------------
__global__ void __launch_bounds__(256) conv_f32_bf16(
    const float* __restrict__ in, u16* __restrict__ out) {
  const size_t i = ((size_t)blockIdx.x * 256 + threadIdx.x) * 4;
  const float4 v = *reinterpret_cast<const float4*>(in + i);
  ushort4 o;
  o.x = f2bf(v.x); o.y = f2bf(v.y); o.z = f2bf(v.z); o.w = f2bf(v.w);
  *reinterpret_cast<ushort4*>(out + i) = o;
}

__global__ void __launch_bounds__(256) conv_all(
    const float* __restrict__ s0, const float* __restrict__ s1,
    const float* __restrict__ s2, const float* __restrict__ s3,
    const float* __restrict__ s4, const float* __restrict__ s5,
    const float* __restrict__ s6,
    u16* __restrict__ d0, u16* __restrict__ d1, u16* __restrict__ d2,
    u16* __restrict__ d3, u16* __restrict__ d4, u16* __restrict__ d5,
    u16* __restrict__ d6, const size_t nact, const size_t nw) {
  const int j = blockIdx.y;
  const size_t i = ((size_t)blockIdx.x * 256 + threadIdx.x) * 4;
  const float* s; u16* d; size_t n;
  switch (j) {
    case 0: s = s0; d = d0; n = nact; break;
    case 1: s = s1; d = d1; n = nact; break;
    case 2: s = s2; d = d2; n = nact; break;
    case 3: s = s3; d = d3; n = nw; break;
    case 4: s = s4; d = d4; n = nw; break;
    case 5: s = s5; d = d5; n = nw; break;
    default: s = s6; d = d6; n = nw; break;
  }
  if (i >= n) return;
  const float4 v = *reinterpret_cast<const float4*>(s + i);
  ushort4 o;
  o.x = f2bf(v.x); o.y = f2bf(v.y); o.z = f2bf(v.z); o.w = f2bf(v.w);
  *reinterpret_cast<ushort4*>(d + i) = o;
}

// ---------------- 8-phase 128x128 GEMM: C = A @ B^T + bias ------------
// K=2048, BK=64 (32 K-tiles, 16 iters x 2 tiles). 256 threads = 4 waves
// (2M x 2N), per-wave C = 64x64 = acc[4][4]. LDS = 2 K-tile dbuf x
// (A 16KB + B 16KB) = 64 KB -> 2 blocks/CU (inter-block overlap hides
// phase stalls; r9's 128KB/1-block lockstep was the bottleneck).
// Each K-tile = two [128 rows][32 k] subtiles (4096 elems), pair-row
// 16B-chunk XOR swizzle (slot ^= rp&7) on the pre-swizzled global
// SOURCE (LDS dest linear); ds_read applies the same XOR (0 conflicts).
// Phase schedule / vmcnt constants identical to r9 derivation:
// ph0,1: stage A(t1); ph2,3: B(t0+2); ph4,5: A(t0+2); ph6,7: B(t1+2);
// vmcnt(6)@ph4 => A(t1),B(t1) landed; vmcnt(4)@ph7 => tile t0+2 landed.
// WAR: every staged region issues >=1 barrier after its last ds_read.
#define GK 2048

DEV void gemm128_core(const u16* __restrict__ A, const u16* __restrict__ Bw,
                      const float* __restrict__ bias, void* __restrict__ Cout,
                      const int m0, const int n0, const int N,
                      const int out_f32, u16* AsB, u16* BsB) {
  const int tid = threadIdx.x;
  const int lane = tid & 63;
  const int wid = tid >> 6;
  const int wr = wid >> 1, wc = wid & 1;
  const int g = lane >> 4;
  const int r16 = lane & 15;

  // staging: subtile = [128 rows][32 k]; 512 chunks of 16B; thread covers
  // G = rr*256 + tid, rr in {0,1}. Source pre-swizzled, LDS linear.
  int offA[2], offB[2], dstE[2];
#pragma unroll
  for (int rr = 0; rr < 2; ++rr) {
    const int G = rr * 256 + tid;
    const int rp = G >> 3;
    const int s = (G & 7) ^ (rp & 7);
    const int row = rp * 2 + (s >> 2);
    const int ch = s & 3;
    offA[rr] = (m0 + row) * GK + ch * 8;
    offB[rr] = (n0 + row) * GK + ch * 8;
    dstE[rr] = rr * 2048 + wid * 512;  // wave-uniform LDS base (elems)
  }

#define STAGE_A(kt, kh) do {                                              \
    u16* base_ = AsB + (((kt) & 1) * 2 + (kh)) * 4096;                    \
    const int go_ = (kt) * 64 + (kh) * 32;                                \
    gload_lds16(A + (size_t)(offA[0] + go_), base_ + dstE[0]);            \
    gload_lds16(A + (size_t)(offA[1] + go_), base_ + dstE[1]);            \
  } while (0)
#define STAGE_B(kt, kh) do {                                              \
    u16* base_ = BsB + (((kt) & 1) * 2 + (kh)) * 4096;                    \
    const int go_ = (kt) * 64 + (kh) * 32;                                \
    gload_lds16(Bw + (size_t)(offB[0] + go_), base_ + dstE[0]);           \
    gload_lds16(Bw + (size_t)(offB[1] + go_), base_ + dstE[1]);           \
  } while (0)
#define READ_A(MH, buf) do {                                              \
    _Pragma("unroll") for (int i_ = 0; i_ < 2; ++i_) {                    \
      const int row_ = wr * 64 + ((MH) * 2 + i_) * 16 + r16;              \
      const int rp_ = row_ >> 1;                                          \
      const int sl_ = (((row_ & 1) << 2) | g) ^ (rp_ & 7);                \
      const int off_ = rp_ * 64 + sl_ * 8;                                \
      af[i_][0] = *(const bf16x8*)(AsB + ((buf) * 2 + 0) * 4096 + off_);  \
      af[i_][1] = *(const bf16x8*)(AsB + ((buf) * 2 + 1) * 4096 + off_);  \
    } } while (0)
#define READ_B(NH, buf, bf) do {                                          \
    _Pragma("unroll") for (int j_ = 0; j_ < 2; ++j_) {                    \
      const int row_ = wc * 64 + ((NH) * 2 + j_) * 16 + r16;              \
      const int rp_ = row_ >> 1;                                          \
      const int sl_ = (((row_ & 1) << 2) | g) ^ (rp_ & 7);                \
      const int off_ = rp_ * 64 + sl_ * 8;                                \
      bf[j_][0] = *(const bf16x8*)(BsB + ((buf) * 2 + 0) * 4096 + off_);  \
      bf[j_][1] = *(const bf16x8*)(BsB + ((buf) * 2 + 1) * 4096 + off_);  \
    } } while (0)
#define MFMA_Q(MH, NH, bf) do {                                           \
    __builtin_amdgcn_s_setprio(1);                                        \
    _Pragma("unroll") for (int i_ = 0; i_ < 2; ++i_)                      \
    _Pragma("unroll") for (int j_ = 0; j_ < 2; ++j_) {                    \
      f32x4 c_ = acc[(MH) * 2 + i_][(NH) * 2 + j_];                       \
      c_ = mfma16(af[i_][0], bf[j_][0], c_);                              \
      c_ = mfma16(af[i_][1], bf[j_][1], c_);                              \
      acc[(MH) * 2 + i_][(NH) * 2 + j_] = c_;                             \
    }                                                                     \
    __builtin_amdgcn_s_setprio(0);                                        \
  } while (0)

  f32x4 acc[4][4];
#pragma unroll
  for (int i = 0; i < 4; ++i)
#pragma unroll
    for (int j = 0; j < 4; ++j) acc[i][j] = {0.f, 0.f, 0.f, 0.f};

  bf16x8 af[2][2], bf0[2][2], bf1[2][2];

  // prologue: tile0 full + B(1); wait tile0 (12 loads -> leave 4)
  STAGE_B(0, 0); STAGE_B(0, 1); STAGE_A(0, 0); STAGE_A(0, 1);
  STAGE_B(1, 0); STAGE_B(1, 1);
  asm volatile("s_waitcnt vmcnt(4)" ::: "memory");
  BAR();

  for (int it = 0; it < 16; ++it) {
    const bool tail = (it == 15);
    const int t0 = 2 * it, t1 = t0 + 1;
    // ph0
    READ_A(0, 0); READ_B(0, 0, bf0);
    STAGE_A(t1, 0);
    BAR(); MFMA_Q(0, 0, bf0); BAR();
    // ph1
    READ_B(1, 0, bf1);
    STAGE_A(t1, 1);
    BAR(); MFMA_Q(0, 1, bf1); BAR();
    // ph2
    READ_A(1, 0);
    if (!tail) STAGE_B(t0 + 2, 0);
    BAR(); MFMA_Q(1, 0, bf0); BAR();
    // ph3
    if (!tail) STAGE_B(t0 + 2, 1);
    BAR(); MFMA_Q(1, 1, bf1); BAR();
    // ph4
    READ_A(0, 1); READ_B(0, 1, bf0);
    if (!tail) {
      STAGE_A(t0 + 2, 0);
      asm volatile("s_waitcnt vmcnt(6)" ::: "memory");
    } else {
      asm volatile("s_waitcnt vmcnt(0)" ::: "memory");
    }
    BAR(); MFMA_Q(0, 0, bf0); BAR();
    // ph5
    READ_B(1, 1, bf1);
    if (!tail) STAGE_A(t0 + 2, 1);
    BAR(); MFMA_Q(0, 1, bf1); BAR();
    // ph6
    READ_A(1, 1);
    if (!tail) STAGE_B(t1 + 2, 0);
    BAR(); MFMA_Q(1, 0, bf0); BAR();
    // ph7
    if (!tail) {
      STAGE_B(t1 + 2, 1);
      asm volatile("s_waitcnt vmcnt(4)" ::: "memory");
    } else {
      asm volatile("s_waitcnt vmcnt(0)" ::: "memory");
    }
    BAR(); MFMA_Q(1, 1, bf1); BAR();
  }

  // epilogue: C/D layout col=lane&15, row=(lane>>4)*4+reg
  const int rbase = m0 + wr * 64 + g * 4;
  const int cb = n0 + wc * 64 + r16;
#pragma unroll
  for (int i = 0; i < 4; ++i) {
#pragma unroll
    for (int j = 0; j < 4; ++j) {
      const int c = cb + j * 16;
      const float bv = bias[c];
#pragma unroll
      for (int r = 0; r < 4; ++r) {
        const float v = acc[i][j][r] + bv;
        const size_t idx = (size_t)(rbase + i * 16 + r) * N + c;
        if (out_f32) ((float*)Cout)[idx] = v;
        else ((u16*)Cout)[idx] = f2bf(v);
      }
    }
  }
#undef STAGE_A
#undef STAGE_B
#undef READ_A
#undef READ_B
#undef MFMA_Q
}

// fused Q/K/V projections: 1536 blocks = 3 x (32m x 16n) = 3 exact
// rounds at 2 blocks/CU. XCD-chunked, m fast (B-panel reuse in L2).
__global__ void __launch_bounds__(256, 2) gemm_qkv3(
    const u16* __restrict__ A0, const u16* __restrict__ A1,
    const u16* __restrict__ A2, const u16* __restrict__ W0,
    const u16* __restrict__ W1, const u16* __restrict__ W2,
    const float* __restrict__ b0, const float* __restrict__ b1,
    const float* __restrict__ b2, u16* __restrict__ C0,
    u16* __restrict__ C1, u16* __restrict__ C2) {
  __shared__ u16 AsB[4 * 4096];  // 32 KB
  __shared__ u16 BsB[4 * 4096];  // 32 KB
  const int logical = (blockIdx.x & 7) * 192 + (blockIdx.x >> 3);
  const int which = logical >> 9;
  const int inner = logical & 511;
  const int m0 = (inner & 31) << 7;
  const int n0 = (inner >> 5) << 7;
  const u16* A = which == 0 ? A0 : which == 1 ? A1 : A2;
  const u16* W = which == 0 ? W0 : which == 1 ? W1 : W2;
  const float* bb = which == 0 ? b0 : which == 1 ? b1 : b2;
  u16* C = which == 0 ? C0 : which == 1 ? C1 : C2;
  gemm128_core(A, W, bb, C, m0, n0, 2048, 0, AsB, BsB);
}

// single GEMM: 512 blocks = 32m x 16n = exactly 1 round at 2 blocks/CU
__global__ void __launch_bounds__(256, 2) gemm_one(
    const u16* __restrict__ A, const u16* __restrict__ Bw,
    const float* __restrict__ bias, void* __restrict__ Cout,
    const int out_f32) {
  __shared__ u16 AsB[4 * 4096];
  __shared__ u16 BsB[4 * 4096];
  const int logical = (blockIdx.x & 7) * 64 + (blockIdx.x >> 3);
  const int m0 = (logical & 31) << 7;
  const int n0 = (logical >> 5) << 7;
  gemm128_core(A, Bw, bias, Cout, m0, n0, 2048, out_f32, AsB, BsB);
}

// ---------------- causal flash attention (swapped QK^T, 32x32) --------
// K-tile LDS double-buffer + counted vmcnt(4): stage K(t+1) at iter
// start; the wait covers {K(t), V(t)} (oldest 8 of 12) without draining
// K(t+1) -> HBM latency spans a full iteration instead of being exposed
// at a vmcnt(0) __syncthreads drain every tile (the r5-r9 flash stall).
#define SEQ 2048
#define DMODEL 2048
#define DH 128
#define QBLK 128
#define KBLK 64
#define C1 0.12751744f   // (1/sqrt(128)) * log2(e)
#define THR_RAW 62.73f   // defer-max threshold: 8 / C1

__global__ void __launch_bounds__(256, 2) flash_attn(
    const u16* __restrict__ Qh, const u16* __restrict__ Kh,
    const u16* __restrict__ Vh, u16* __restrict__ O) {
  __shared__ u16 Ks[2][KBLK * DH];  // 32 KB
  __shared__ u16 Vt[DH * KBLK];     // 16 KB

  const int tid = threadIdx.x;
  const int lane = tid & 63;
  const int w = tid >> 6;
  const int hi = lane >> 5;
  const int l31 = lane & 31;

  const int cc = blockIdx.x;
  const int low = cc & 15;
  const int bh = (cc >> 4) & 31;
  const int h = bh & 15;
  const int b = bh >> 4;
  const int g0 = low ^ h;
  const int qt = b ? (15 - g0) : g0;
  const int q0 = qt * QBLK;
  const size_t rowbase = (size_t)b * SEQ;
  const int hoff = h * DH;
  const int qw = q0 + w * 32;
  const int qlane = qw + l31;

  bf16x8 aq[8];
  {
    const u16* qp = &Qh[(rowbase + qlane) * DMODEL + hoff + hi * 8];
#pragma unroll
    for (int c = 0; c < 8; ++c)
      aq[c] = *reinterpret_cast<const bf16x8*>(qp + c * 16);
  }

  f32x16 oacc[4];
#pragma unroll
  for (int dt = 0; dt < 4; ++dt)
#pragma unroll
    for (int r = 0; r < 16; ++r) oacc[dt][r] = 0.f;
  float mrow = -1e30f, lrow = 0.f;

  const int krl = w * 16 + (lane >> 4);
  const int kg4 = w * 4 + (lane >> 4);
  const int du = lane & 15;

  const int nkt = 2 * qt + 2;
  const int ktd = qw >> 6;

  // stage K tile kt into Ks[kt&1] (pre-swizzled source, linear dest)
  auto stageK = [&](int kt) {
#pragma unroll
    for (int i = 0; i < 4; ++i) {
      const int r = krl + i * 4;
      const int cg = (lane & 15) ^ (r & 15);
      gload_lds16(&Kh[(rowbase + kt * KBLK + r) * DMODEL + hoff + cg * 8],
                  &Ks[kt & 1][(w * 16 + i * 4) * DH]);
    }
  };

  // prologue: K(0) in flight, V(0) -> regs
  stageK(0);
  uint4 vv[4];
#pragma unroll
  for (int r = 0; r < 4; ++r)
    vv[r] = *reinterpret_cast<const uint4*>(
        &Vh[(rowbase + kg4 * 4 + r) * DMODEL + hoff + du * 8]);

  for (int kt = 0; kt < nkt; ++kt) {
    const int k0 = kt * KBLK;
    if (kt + 1 < nkt) {
      stageK(kt + 1);
      // oldest 8 of {K(kt),V(kt),K(kt+1)} done: K(kt) landed, vv ready
      asm volatile("s_waitcnt vmcnt(4)" ::: "memory");
    } else {
      asm volatile("s_waitcnt vmcnt(0)" ::: "memory");
    }

    // V transpose from regs: 8x b64 swizzled writes
#pragma unroll
    for (int j = 0; j < 8; ++j) {
      const int d = du * 8 + j;
      ushort4 pk4;
      pk4.x = ((const u16*)&vv[0])[j];
      pk4.y = ((const u16*)&vv[1])[j];
      pk4.z = ((const u16*)&vv[2])[j];
      pk4.w = ((const u16*)&vv[3])[j];
      const int slot = (((kg4 >> 1) ^ ((d >> 2) & 7)) * 8) + (kg4 & 1) * 4;
      *reinterpret_cast<ushort4*>(&Vt[d * KBLK + slot]) = pk4;
    }
    asm volatile("s_waitcnt lgkmcnt(0)" ::: "memory");
    BAR();  // Ks[kt&1] + Vt ready for all waves

    const bool active = (kt <= ktd);
    const u16* kb = &Ks[kt & 1][0];
    float p[2][16];
    bool act1 = false;

    if (active) {
      const bool diag = (kt == ktd);
      act1 = (kt < ktd) || (w & 1);
      const bool m0q = diag && !(w & 1);
      const bool m1q = diag && (w & 1);
      {
        f32x16 s;
#pragma unroll
        for (int r = 0; r < 16; ++r) s[r] = 0.f;
        __builtin_amdgcn_s_setprio(1);
#pragma unroll
        for (int c = 0; c < 8; ++c) {
          const int row = l31;
          const bf16x8 kf = *reinterpret_cast<const bf16x8*>(
              &kb[row * DH + (((c * 2 + hi) ^ (row & 15)) * 8)]);
          s = mfma32(kf, aq[c], s);
        }
        __builtin_amdgcn_s_setprio(0);
#pragma unroll
        for (int r = 0; r < 16; ++r) {
          const int krow = (r & 3) + 8 * (r >> 2) + 4 * hi;
          p[0][r] = (m0q && (k0 + krow > qlane)) ? -1e9f : s[r];
        }
      }
      if (act1) {
        f32x16 s;
#pragma unroll
        for (int r = 0; r < 16; ++r) s[r] = 0.f;
        __builtin_amdgcn_s_setprio(1);
#pragma unroll
        for (int c = 0; c < 8; ++c) {
          const int row = 32 + l31;
          const bf16x8 kf = *reinterpret_cast<const bf16x8*>(
              &kb[row * DH + (((c * 2 + hi) ^ (row & 15)) * 8)]);
          s = mfma32(kf, aq[c], s);
        }
        __builtin_amdgcn_s_setprio(0);
#pragma unroll
        for (int r = 0; r < 16; ++r) {
          const int krow = (r & 3) + 8 * (r >> 2) + 4 * hi;
          p[1][r] = (m1q && (k0 + 32 + krow > qlane)) ? -1e9f : s[r];
        }
      } else {
#pragma unroll
        for (int r = 0; r < 16; ++r) p[1][r] = -1e9f;
      }
    }

    // prefetch next tile's V rows (hidden under softmax/PV)
    if (kt + 1 < nkt) {
#pragma unroll
      for (int r = 0; r < 4; ++r)
        vv[r] = *reinterpret_cast<const uint4*>(
            &Vh[(rowbase + k0 + KBLK + kg4 * 4 + r) * DMODEL + hoff + du * 8]);
    }

    if (active) {
      float mx = fmaxf(p[0][0], p[0][1]);
#pragma unroll
      for (int r = 2; r < 16; ++r) mx = fmaxf(mx, p[0][r]);
#pragma unroll
      for (int r = 0; r < 16; ++r) mx = fmaxf(mx, p[1][r]);
      mx = fmaxf(mx, __shfl_xor(mx, 32));

      const bool need = (mx > mrow + THR_RAW);
      if (__any((int)need)) {
        const float mn = fmaxf(mrow, mx);
        const float al = exp2f((mrow - mn) * C1);
        mrow = mn;
        lrow *= al;
#pragma unroll
        for (int r = 0; r < 16; ++r) {
          const float ar = __shfl(al, (r & 3) + 8 * (r >> 2) + 4 * hi);
#pragma unroll
          for (int dt = 0; dt < 4; ++dt) oacc[dt][r] *= ar;
        }
      }

      float sum = 0.f;
#pragma unroll
      for (int t = 0; t < 2; ++t)
#pragma unroll
        for (int r = 0; r < 16; ++r) {
          p[t][r] = exp2f((p[t][r] - mrow) * C1);
          sum += p[t][r];
        }
      sum += __shfl_xor(sum, 32);
      lrow += sum;

      u32 pk[2][8];
#pragma unroll
      for (int t = 0; t < 2; ++t)
#pragma unroll
        for (int m = 0; m < 8; ++m)
          pk[t][m] = pack2(p[t][2 * m], p[t][2 * m + 1]);

      __builtin_amdgcn_s_setprio(1);
#pragma unroll
      for (int ks = 0; ks < 4; ++ks) {
        if (ks >= 2 && !act1) break;
        const int t = ks >> 1;
        const int bs = (ks & 1) * 4;
        const u32 s0 = __shfl_xor(pk[t][bs + 0], 32);
        const u32 s1 = __shfl_xor(pk[t][bs + 1], 32);
        const u32 s2 = __shfl_xor(pk[t][bs + 2], 32);
        const u32 s3 = __shfl_xor(pk[t][bs + 3], 32);
        union { u32 u[4]; bf16x8 v; } pa;
        pa.u[0] = hi ? s2 : pk[t][bs + 0];
        pa.u[1] = hi ? s3 : pk[t][bs + 1];
        pa.u[2] = hi ? pk[t][bs + 2] : s0;
        pa.u[3] = hi ? pk[t][bs + 3] : s1;
#pragma unroll
        for (int dt = 0; dt < 4; ++dt) {
          const int d = dt * 32 + l31;
          const bf16x8 vf = *reinterpret_cast<const bf16x8*>(
              &Vt[d * KBLK + (((ks * 2 + hi) ^ ((d >> 2) & 7)) * 8)]);
          oacc[dt] = mfma32(pa.v, vf, oacc[dt]);
        }
      }
      __builtin_amdgcn_s_setprio(0);
    }

    BAR();  // all LDS reads of this tile complete before next overwrite
  }

  const float li = __builtin_amdgcn_rcpf(lrow);
#pragma unroll
  for (int r = 0; r < 16; ++r) {
    const int rowq = (r & 3) + 8 * (r >> 2) + 4 * hi;
    const float lr = __shfl(li, rowq);
    u16* op = &O[(rowbase + qw + rowq) * DMODEL + hoff + l31];
#pragma unroll
    for (int dt = 0; dt < 4; ++dt) op[dt * 32] = f2bf(oacc[dt][r] * lr);
  }
}

// ---------------- launcher --------------------------------------------
extern "C" void kernel_launch(void* const* d_in, const int* in_sizes, int n_in,
                              void* d_out, int out_size, void* d_ws,
                              size_t ws_size, hipStream_t stream) {
  const int Bv = 2, S = 2048, D = 2048;
  const int M = Bv * S;
  const size_t NT = (size_t)M * D;   // 8388608
  const size_t NW = (size_t)D * D;   // 4194304

  const float* q = (const float*)d_in[0];
  const float* k = (const float*)d_in[1];
  const float* v = (const float*)d_in[2];
  const float* wq_w = (const float*)d_in[4];
  const float* wq_b = (const float*)d_in[5];
  const float* wk_w = (const float*)d_in[6];
  const float* wk_b = (const float*)d_in[7];
  const float* wv_w = (const float*)d_in[8];
  const float* wv_b = (const float*)d_in[9];
  const float* dw = (const float*)d_in[10];
  const float* db = (const float*)d_in[11];
  float* out = (float*)d_out;

  const dim3 blk(256);
  const dim3 gattn(512);
  const size_t need = (7 * NT + 4 * NW) * 2;  // ~151 MB

  if (ws_size >= need) {
    u16* base = (u16*)d_ws;
    u16* Xq = base;
    u16* Xk = Xq + NT;
    u16* Xv = Xk + NT;
    u16* Wq = Xv + NT;
    u16* Wk = Wq + NW;
    u16* Wv = Wk + NW;
    u16* Wd = Wv + NW;
    u16* Qh = Wd + NW;
    u16* Kh = Qh + NT;
    u16* Vh = Kh + NT;
    u16* Obf = Vh + NT;

    conv_all<<<dim3((unsigned)(NT / 1024), 7), blk, 0, stream>>>(
        q, k, v, wq_w, wk_w, wv_w, dw, Xq, Xk, Xv, Wq, Wk, Wv, Wd, NT, NW);
    gemm_qkv3<<<dim3(1536), blk, 0, stream>>>(
        Xq, Xk, Xv, Wq, Wk, Wv, wq_b, wk_b, wv_b, Qh, Kh, Vh);
    flash_attn<<<gattn, blk, 0, stream>>>(Qh, Kh, Vh, Obf);
    gemm_one<<<dim3(512), blk, 0, stream>>>(Obf, Wd, db, out, 1);
  } else {
    u16* Xbf = (u16*)d_ws;
    u16* Wbf = Xbf + NT;
    u16* Qh = Wbf + NW;
    u16* Kh = Qh + NT;
    u16* Vh = Kh + NT;
    u16* Obf = Vh + NT;
    const dim3 gact((unsigned)(NT / 1024));
    const dim3 gw((unsigned)(NW / 1024));

    conv_f32_bf16<<<gact, blk, 0, stream>>>(q, Xbf);
    conv_f32_bf16<<<gw, blk, 0, stream>>>(wq_w, Wbf);
    gemm_one<<<dim3(512), blk, 0, stream>>>(Xbf, Wbf, wq_b, Qh, 0);
    conv_f32_bf16<<<gact, blk, 0, stream>>>(k, Xbf);
    conv_f32_bf16<<<gw, blk, 0, stream>>>(wk_w, Wbf);
    gemm_one<<<dim3(512), blk, 0, stream>>>(Xbf, Wbf, wk_b, Kh, 0);
    conv_f32_bf16<<<gact, blk, 0, stream>>>(v, Xbf);
    conv_f32_bf16<<<gw, blk, 0, stream>>>(wv_w, Wbf);
    gemm_one<<<dim3(512), blk, 0, stream>>>(Xbf, Wbf, wv_b, Vh, 0);
    flash_attn<<<gattn, blk, 0, stream>>>(Qh, Kh, Vh, Obf);
    conv_f32_bf16<<<gw, blk, 0, stream>>>(dw, Wbf);
    gemm_one<<<dim3(512), blk, 0, stream>>>(Obf, Wbf, db, out, 1);
  }
}

// Round 12
// 298.340 us; speedup vs baseline: 1.0832x; 1.0832x over previous
//
#include <hip/hip_runtime.h>
#include <hip/hip_bf16.h>

// GPT3 attention block, B=2 S=2048 D=2048 H=16 Dh=128.
// 8-phase 128x128 counted-vmcnt GEMM (2 blocks/CU, L2/L3-aware XCD map)
// + swapped-QK^T 32x32 flash attention with K-tile double-buffer.

typedef __bf16 bf16x8 __attribute__((ext_vector_type(8)));
typedef float f32x4 __attribute__((ext_vector_type(4)));
typedef float f32x16 __attribute__((ext_vector_type(16)));
typedef unsigned short u16;
typedef unsigned int u32;

#define DEV static __device__ __forceinline__

DEV void gload_lds16(const void* g, void* l) {
  __builtin_amdgcn_global_load_lds(
      (const __attribute__((address_space(1))) void*)g,
      (__attribute__((address_space(3))) void*)l, 16, 0, 0);
}

DEV f32x4 mfma16(bf16x8 a, bf16x8 b, f32x4 c) {
  return __builtin_amdgcn_mfma_f32_16x16x32_bf16(a, b, c, 0, 0, 0);
}

DEV f32x16 mfma32(bf16x8 a, bf16x8 b, f32x16 c) {
  return __builtin_amdgcn_mfma_f32_32x32x16_bf16(a, b, c, 0, 0, 0);
}

DEV u16 f2bf(float x) {
  return __builtin_bit_cast(u16, __float2bfloat16(x));
}

DEV u32 pack2(float lo, float hi_) {
  return (u32)f2bf(lo) | ((u32)f2bf(hi_) << 16);
}

#define BAR() __builtin_amdgcn_s_barrier()

// ---------------- fp32 -> bf16 conversion ----------------------------
__global__ void __launch_bounds__(256) conv_f32_bf16(
    const float* __restrict__ in, u16* __restrict__ out) {
  const size_t i = ((size_t)blockIdx.x * 256 + threadIdx.x) * 4;
  const float4 v = *reinterpret_cast<const float4*>(in + i);
  ushort4 o;
  o.x = f2bf(v.x); o.y = f2bf(v.y); o.z = f2bf(v.z); o.w = f2bf(v.w);
  *reinterpret_cast<ushort4*>(out + i) = o;
}

__global__ void __launch_bounds__(256) conv_all(
    const float* __restrict__ s0, const float* __restrict__ s1,
    const float* __restrict__ s2, const float* __restrict__ s3,
    const float* __restrict__ s4, const float* __restrict__ s5,
    const float* __restrict__ s6,
    u16* __restrict__ d0, u16* __restrict__ d1, u16* __restrict__ d2,
    u16* __restrict__ d3, u16* __restrict__ d4, u16* __restrict__ d5,
    u16* __restrict__ d6, const size_t nact, const size_t nw) {
  const int j = blockIdx.y;
  const size_t i = ((size_t)blockIdx.x * 256 + threadIdx.x) * 4;
  const float* s; u16* d; size_t n;
  switch (j) {
    case 0: s = s0; d = d0; n = nact; break;
    case 1: s = s1; d = d1; n = nact; break;
    case 2: s = s2; d = d2; n = nact; break;
    case 3: s = s3; d = d3; n = nw; break;
    case 4: s = s4; d = d4; n = nw; break;
    case 5: s = s5; d = d5; n = nw; break;
    default: s = s6; d = d6; n = nw; break;
  }
  if (i >= n) return;
  const float4 v = *reinterpret_cast<const float4*>(s + i);
  ushort4 o;
  o.x = f2bf(v.x); o.y = f2bf(v.y); o.z = f2bf(v.z); o.w = f2bf(v.w);
  *reinterpret_cast<ushort4*>(d + i) = o;
}

// ---------------- 8-phase 128x128 GEMM: C = A @ B^T + bias ------------
// K=2048, BK=64 (32 K-tiles, 16 iters x 2 tiles). 256 threads = 4 waves
// (2M x 2N), per-wave C = 64x64 = acc[4][4]. LDS 64 KB -> 2 blocks/CU.
// Pair-row 16B-chunk XOR swizzle on pre-swizzled global SOURCE (LDS dest
// linear for global_load_lds); ds_read applies the same XOR (0 conflicts).
// Stage schedule: ph0,1: A(t1); ph2,3: B(t0+2); ph4,5: A(t0+2);
// ph6,7: B(t1+2). Waits (FIXED r12: wait must retire a buffer BEFORE the
// first ds_read touching it, i.e. at the END of the preceding phase):
//   ph3: vmcnt(4)  -> retires B(t1)+A(t1) (8 oldest of 12) before ph4-6
//                     read buf1; tail iter: vmcnt(0).
//   ph7: vmcnt(4)  -> retires B(t0+2)+A(t0+2) before next-iter ph0-2
//                     read buf0; tail iter: vmcnt(0).
// r11 had the ph4 wait AFTER the buf1 ds_reads - correct only by latency.
#define GK 2048

DEV void gemm128_core(const u16* __restrict__ A, const u16* __restrict__ Bw,
                      const float* __restrict__ bias, void* __restrict__ Cout,
                      const int m0, const int n0, const int N,
                      const int out_f32, u16* AsB, u16* BsB) {
  const int tid = threadIdx.x;
  const int lane = tid & 63;
  const int wid = tid >> 6;
  const int wr = wid >> 1, wc = wid & 1;
  const int g = lane >> 4;
  const int r16 = lane & 15;

  int offA[2], offB[2], dstE[2];
#pragma unroll
  for (int rr = 0; rr < 2; ++rr) {
    const int G = rr * 256 + tid;
    const int rp = G >> 3;
    const int s = (G & 7) ^ (rp & 7);
    const int row = rp * 2 + (s >> 2);
    const int ch = s & 3;
    offA[rr] = (m0 + row) * GK + ch * 8;
    offB[rr] = (n0 + row) * GK + ch * 8;
    dstE[rr] = rr * 2048 + wid * 512;
  }

#define STAGE_A(kt, kh) do {                                              \
    u16* base_ = AsB + (((kt) & 1) * 2 + (kh)) * 4096;                    \
    const int go_ = (kt) * 64 + (kh) * 32;                                \
    gload_lds16(A + (size_t)(offA[0] + go_), base_ + dstE[0]);            \
    gload_lds16(A + (size_t)(offA[1] + go_), base_ + dstE[1]);            \
  } while (0)
#define STAGE_B(kt, kh) do {                                              \
    u16* base_ = BsB + (((kt) & 1) * 2 + (kh)) * 4096;                    \
    const int go_ = (kt) * 64 + (kh) * 32;                                \
    gload_lds16(Bw + (size_t)(offB[0] + go_), base_ + dstE[0]);           \
    gload_lds16(Bw + (size_t)(offB[1] + go_), base_ + dstE[1]);           \
  } while (0)
#define READ_A(MH, buf) do {                                              \
    _Pragma("unroll") for (int i_ = 0; i_ < 2; ++i_) {                    \
      const int row_ = wr * 64 + ((MH) * 2 + i_) * 16 + r16;              \
      const int rp_ = row_ >> 1;                                          \
      const int sl_ = (((row_ & 1) << 2) | g) ^ (rp_ & 7);                \
      const int off_ = rp_ * 64 + sl_ * 8;                                \
      af[i_][0] = *(const bf16x8*)(AsB + ((buf) * 2 + 0) * 4096 + off_);  \
      af[i_][1] = *(const bf16x8*)(AsB + ((buf) * 2 + 1) * 4096 + off_);  \
    } } while (0)
#define READ_B(NH, buf, bf) do {                                          \
    _Pragma("unroll") for (int j_ = 0; j_ < 2; ++j_) {                    \
      const int row_ = wc * 64 + ((NH) * 2 + j_) * 16 + r16;              \
      const int rp_ = row_ >> 1;                                          \
      const int sl_ = (((row_ & 1) << 2) | g) ^ (rp_ & 7);                \
      const int off_ = rp_ * 64 + sl_ * 8;                                \
      bf[j_][0] = *(const bf16x8*)(BsB + ((buf) * 2 + 0) * 4096 + off_);  \
      bf[j_][1] = *(const bf16x8*)(BsB + ((buf) * 2 + 1) * 4096 + off_);  \
    } } while (0)
#define MFMA_Q(MH, NH, bf) do {                                           \
    __builtin_amdgcn_s_setprio(1);                                        \
    _Pragma("unroll") for (int i_ = 0; i_ < 2; ++i_)                      \
    _Pragma("unroll") for (int j_ = 0; j_ < 2; ++j_) {                    \
      f32x4 c_ = acc[(MH) * 2 + i_][(NH) * 2 + j_];                       \
      c_ = mfma16(af[i_][0], bf[j_][0], c_);                              \
      c_ = mfma16(af[i_][1], bf[j_][1], c_);                              \
      acc[(MH) * 2 + i_][(NH) * 2 + j_] = c_;                             \
    }                                                                     \
    __builtin_amdgcn_s_setprio(0);                                        \
  } while (0)

  f32x4 acc[4][4];
#pragma unroll
  for (int i = 0; i < 4; ++i)
#pragma unroll
    for (int j = 0; j < 4; ++j) acc[i][j] = {0.f, 0.f, 0.f, 0.f};

  bf16x8 af[2][2], bf0[2][2], bf1[2][2];

  // prologue: tile0 full + B(1); vmcnt(4) retires tile0's 8 loads
  STAGE_B(0, 0); STAGE_B(0, 1); STAGE_A(0, 0); STAGE_A(0, 1);
  STAGE_B(1, 0); STAGE_B(1, 1);
  asm volatile("s_waitcnt vmcnt(4)" ::: "memory");
  BAR();

  for (int it = 0; it < 16; ++it) {
    const bool tail = (it == 15);
    const int t0 = 2 * it, t1 = t0 + 1;
    // ph0  (reads buf0 = t0: guaranteed by prev ph7 / prologue wait)
    READ_A(0, 0); READ_B(0, 0, bf0);
    STAGE_A(t1, 0);
    BAR(); MFMA_Q(0, 0, bf0); BAR();
    // ph1
    READ_B(1, 0, bf1);
    STAGE_A(t1, 1);
    BAR(); MFMA_Q(0, 1, bf1); BAR();
    // ph2
    READ_A(1, 0);
    if (!tail) STAGE_B(t0 + 2, 0);
    BAR(); MFMA_Q(1, 0, bf0); BAR();
    // ph3  (wait HERE so buf1 = t1 is landed before ph4's ds_reads)
    if (!tail) {
      STAGE_B(t0 + 2, 1);
      asm volatile("s_waitcnt vmcnt(4)" ::: "memory");
    } else {
      asm volatile("s_waitcnt vmcnt(0)" ::: "memory");
    }
    BAR(); MFMA_Q(1, 1, bf1); BAR();
    // ph4  (reads buf1 = t1: safe)
    READ_A(0, 1); READ_B(0, 1, bf0);
    if (!tail) STAGE_A(t0 + 2, 0);
    BAR(); MFMA_Q(0, 0, bf0); BAR();
    // ph5
    READ_B(1, 1, bf1);
    if (!tail) STAGE_A(t0 + 2, 1);
    BAR(); MFMA_Q(0, 1, bf1); BAR();
    // ph6
    READ_A(1, 1);
    if (!tail) STAGE_B(t1 + 2, 0);
    BAR(); MFMA_Q(1, 0, bf0); BAR();
    // ph7  (wait so buf0 = t0+2 is landed before next-iter ph0 reads)
    if (!tail) {
      STAGE_B(t1 + 2, 1);
      asm volatile("s_waitcnt vmcnt(4)" ::: "memory");
    } else {
      asm volatile("s_waitcnt vmcnt(0)" ::: "memory");
    }
    BAR(); MFMA_Q(1, 1, bf1); BAR();
  }

  // epilogue: C/D layout col=lane&15, row=(lane>>4)*4+reg
  const int rbase = m0 + wr * 64 + g * 4;
  const int cb = n0 + wc * 64 + r16;
#pragma unroll
  for (int i = 0; i < 4; ++i) {
#pragma unroll
    for (int j = 0; j < 4; ++j) {
      const int c = cb + j * 16;
      const float bv = bias[c];
#pragma unroll
      for (int r = 0; r < 4; ++r) {
        const float v = acc[i][j][r] + bv;
        const size_t idx = (size_t)(rbase + i * 16 + r) * N + c;
        if (out_f32) ((float*)Cout)[idx] = v;
        else ((u16*)Cout)[idx] = f2bf(v);
      }
    }
  }
#undef STAGE_A
#undef STAGE_B
#undef READ_A
#undef READ_B
#undef MFMA_Q
}

// L2/L3-aware XCD map: per XCD, chunk = 4 m-panels x 16 n (n fast).
// XCD's A-slab = 4x128 rows x 2048 x 2B = 2 MB -> resident in its 4 MB
// L2; B (8 MB) is identical across XCDs -> L3-resident, read once.
// fused Q/K/V projections: 1536 blocks = 3 exact rounds at 2 blocks/CU;
// `which` slowest per XCD so one A-slab+B pair is hot at a time.
__global__ void __launch_bounds__(256, 2) gemm_qkv3(
    const u16* __restrict__ A0, const u16* __restrict__ A1,
    const u16* __restrict__ A2, const u16* __restrict__ W0,
    const u16* __restrict__ W1, const u16* __restrict__ W2,
    const float* __restrict__ b0, const float* __restrict__ b1,
    const float* __restrict__ b2, u16* __restrict__ C0,
    u16* __restrict__ C1, u16* __restrict__ C2) {
  __shared__ u16 AsB[4 * 4096];  // 32 KB
  __shared__ u16 BsB[4 * 4096];  // 32 KB
  const int xcd = blockIdx.x & 7;
  const int t = blockIdx.x >> 3;      // 0..191
  const int which = t >> 6;           // 0..2
  const int r = t & 63;
  const int m0 = (xcd * 4 + (r >> 4)) << 7;  // 4 m-panels per XCD
  const int n0 = (r & 15) << 7;              // n fast
  const u16* A = which == 0 ? A0 : which == 1 ? A1 : A2;
  const u16* W = which == 0 ? W0 : which == 1 ? W1 : W2;
  const float* bb = which == 0 ? b0 : which == 1 ? b1 : b2;
  u16* C = which == 0 ? C0 : which == 1 ? C1 : C2;
  gemm128_core(A, W, bb, C, m0, n0, 2048, 0, AsB, BsB);
}

// single GEMM: 512 blocks = 1 exact round at 2 blocks/CU
__global__ void __launch_bounds__(256, 2) gemm_one(
    const u16* __restrict__ A, const u16* __restrict__ Bw,
    const float* __restrict__ bias, void* __restrict__ Cout,
    const int out_f32) {
  __shared__ u16 AsB[4 * 4096];
  __shared__ u16 BsB[4 * 4096];
  const int xcd = blockIdx.x & 7;
  const int t = blockIdx.x >> 3;      // 0..63
  const int m0 = (xcd * 4 + (t >> 4)) << 7;
  const int n0 = (t & 15) << 7;
  gemm128_core(A, Bw, bias, Cout, m0, n0, 2048, out_f32, AsB, BsB);
}

// ---------------- causal flash attention (swapped QK^T, 32x32) --------
#define SEQ 2048
#define DMODEL 2048
#define DH 128
#define QBLK 128
#define KBLK 64
#define C1 0.12751744f   // (1/sqrt(128)) * log2(e)
#define THR_RAW 62.73f   // defer-max threshold: 8 / C1

__global__ void __launch_bounds__(256, 2) flash_attn(
    const u16* __restrict__ Qh, const u16* __restrict__ Kh,
    const u16* __restrict__ Vh, u16* __restrict__ O) {
  __shared__ u16 Ks[2][KBLK * DH];  // 32 KB
  __shared__ u16 Vt[DH * KBLK];     // 16 KB

  const int tid = threadIdx.x;
  const int lane = tid & 63;
  const int w = tid >> 6;
  const int hi = lane >> 5;
  const int l31 = lane & 31;

  const int cc = blockIdx.x;
  const int low = cc & 15;
  const int bh = (cc >> 4) & 31;
  const int h = bh & 15;
  const int b = bh >> 4;
  const int g0 = low ^ h;
  const int qt = b ? (15 - g0) : g0;
  const int q0 = qt * QBLK;
  const size_t rowbase = (size_t)b * SEQ;
  const int hoff = h * DH;
  const int qw = q0 + w * 32;
  const int qlane = qw + l31;

  bf16x8 aq[8];
  {
    const u16* qp = &Qh[(rowbase + qlane) * DMODEL + hoff + hi * 8];
#pragma unroll
    for (int c = 0; c < 8; ++c)
      aq[c] = *reinterpret_cast<const bf16x8*>(qp + c * 16);
  }

  f32x16 oacc[4];
#pragma unroll
  for (int dt = 0; dt < 4; ++dt)
#pragma unroll
    for (int r = 0; r < 16; ++r) oacc[dt][r] = 0.f;
  float mrow = -1e30f, lrow = 0.f;

  const int krl = w * 16 + (lane >> 4);
  const int kg4 = w * 4 + (lane >> 4);
  const int du = lane & 15;

  const int nkt = 2 * qt + 2;
  const int ktd = qw >> 6;

  auto stageK = [&](int kt) {
#pragma unroll
    for (int i = 0; i < 4; ++i) {
      const int r = krl + i * 4;
      const int cg = (lane & 15) ^ (r & 15);
      gload_lds16(&Kh[(rowbase + kt * KBLK + r) * DMODEL + hoff + cg * 8],
                  &Ks[kt & 1][(w * 16 + i * 4) * DH]);
    }
  };

  stageK(0);
  uint4 vv[4];
#pragma unroll
  for (int r = 0; r < 4; ++r)
    vv[r] = *reinterpret_cast<const uint4*>(
        &Vh[(rowbase + kg4 * 4 + r) * DMODEL + hoff + du * 8]);

  for (int kt = 0; kt < nkt; ++kt) {
    const int k0 = kt * KBLK;
    if (kt + 1 < nkt) {
      stageK(kt + 1);
      asm volatile("s_waitcnt vmcnt(4)" ::: "memory");
    } else {
      asm volatile("s_waitcnt vmcnt(0)" ::: "memory");
    }

#pragma unroll
    for (int j = 0; j < 8; ++j) {
      const int d = du * 8 + j;
      ushort4 pk4;
      pk4.x = ((const u16*)&vv[0])[j];
      pk4.y = ((const u16*)&vv[1])[j];
      pk4.z = ((const u16*)&vv[2])[j];
      pk4.w = ((const u16*)&vv[3])[j];
      const int slot = (((kg4 >> 1) ^ ((d >> 2) & 7)) * 8) + (kg4 & 1) * 4;
      *reinterpret_cast<ushort4*>(&Vt[d * KBLK + slot]) = pk4;
    }
    asm volatile("s_waitcnt lgkmcnt(0)" ::: "memory");
    BAR();

    const bool active = (kt <= ktd);
    const u16* kb = &Ks[kt & 1][0];
    float p[2][16];
    bool act1 = false;

    if (active) {
      const bool diag = (kt == ktd);
      act1 = (kt < ktd) || (w & 1);
      const bool m0q = diag && !(w & 1);
      const bool m1q = diag && (w & 1);
      {
        f32x16 s;
#pragma unroll
        for (int r = 0; r < 16; ++r) s[r] = 0.f;
        __builtin_amdgcn_s_setprio(1);
#pragma unroll
        for (int c = 0; c < 8; ++c) {
          const int row = l31;
          const bf16x8 kf = *reinterpret_cast<const bf16x8*>(
              &kb[row * DH + (((c * 2 + hi) ^ (row & 15)) * 8)]);
          s = mfma32(kf, aq[c], s);
        }
        __builtin_amdgcn_s_setprio(0);
#pragma unroll
        for (int r = 0; r < 16; ++r) {
          const int krow = (r & 3) + 8 * (r >> 2) + 4 * hi;
          p[0][r] = (m0q && (k0 + krow > qlane)) ? -1e9f : s[r];
        }
      }
      if (act1) {
        f32x16 s;
#pragma unroll
        for (int r = 0; r < 16; ++r) s[r] = 0.f;
        __builtin_amdgcn_s_setprio(1);
#pragma unroll
        for (int c = 0; c < 8; ++c) {
          const int row = 32 + l31;
          const bf16x8 kf = *reinterpret_cast<const bf16x8*>(
              &kb[row * DH + (((c * 2 + hi) ^ (row & 15)) * 8)]);
          s = mfma32(kf, aq[c], s);
        }
        __builtin_amdgcn_s_setprio(0);
#pragma unroll
        for (int r = 0; r < 16; ++r) {
          const int krow = (r & 3) + 8 * (r >> 2) + 4 * hi;
          p[1][r] = (m1q && (k0 + 32 + krow > qlane)) ? -1e9f : s[r];
        }
      } else {
#pragma unroll
        for (int r = 0; r < 16; ++r) p[1][r] = -1e9f;
      }
    }

    if (kt + 1 < nkt) {
#pragma unroll
      for (int r = 0; r < 4; ++r)
        vv[r] = *reinterpret_cast<const uint4*>(
            &Vh[(rowbase + k0 + KBLK + kg4 * 4 + r) * DMODEL + hoff + du * 8]);
    }

    if (active) {
      // 4-chain max reduction (ILP + v_max3 fusion)
      float mx0 = fmaxf(p[0][0], p[1][0]);
      float mx1 = fmaxf(p[0][1], p[1][1]);
      float mx2 = fmaxf(p[0][2], p[1][2]);
      float mx3 = fmaxf(p[0][3], p[1][3]);
#pragma unroll
      for (int r = 4; r < 16; r += 4) {
        mx0 = fmaxf(mx0, fmaxf(p[0][r + 0], p[1][r + 0]));
        mx1 = fmaxf(mx1, fmaxf(p[0][r + 1], p[1][r + 1]));
        mx2 = fmaxf(mx2, fmaxf(p[0][r + 2], p[1][r + 2]));
        mx3 = fmaxf(mx3, fmaxf(p[0][r + 3], p[1][r + 3]));
      }
      float mx = fmaxf(fmaxf(mx0, mx1), fmaxf(mx2, mx3));
      mx = fmaxf(mx, __shfl_xor(mx, 32));

      const bool need = (mx > mrow + THR_RAW);
      if (__any((int)need)) {
        const float mn = fmaxf(mrow, mx);
        const float al = exp2f((mrow - mn) * C1);
        mrow = mn;
        lrow *= al;
#pragma unroll
        for (int r = 0; r < 16; ++r) {
          const float ar = __shfl(al, (r & 3) + 8 * (r >> 2) + 4 * hi);
#pragma unroll
          for (int dt = 0; dt < 4; ++dt) oacc[dt][r] *= ar;
        }
      }

      // exps + 4-chain sum
      float s0 = 0.f, s1 = 0.f, s2 = 0.f, s3 = 0.f;
#pragma unroll
      for (int t = 0; t < 2; ++t)
#pragma unroll
        for (int r = 0; r < 16; r += 4) {
          p[t][r + 0] = exp2f((p[t][r + 0] - mrow) * C1);
          p[t][r + 1] = exp2f((p[t][r + 1] - mrow) * C1);
          p[t][r + 2] = exp2f((p[t][r + 2] - mrow) * C1);
          p[t][r + 3] = exp2f((p[t][r + 3] - mrow) * C1);
          s0 += p[t][r + 0]; s1 += p[t][r + 1];
          s2 += p[t][r + 2]; s3 += p[t][r + 3];
        }
      float sum = (s0 + s1) + (s2 + s3);
      sum += __shfl_xor(sum, 32);
      lrow += sum;

      u32 pk[2][8];
#pragma unroll
      for (int t = 0; t < 2; ++t)
#pragma unroll
        for (int m = 0; m < 8; ++m)
          pk[t][m] = pack2(p[t][2 * m], p[t][2 * m + 1]);

      __builtin_amdgcn_s_setprio(1);
#pragma unroll
      for (int ks = 0; ks < 4; ++ks) {
        if (ks >= 2 && !act1) break;
        const int t = ks >> 1;
        const int bs = (ks & 1) * 4;
        const u32 q0s = __shfl_xor(pk[t][bs + 0], 32);
        const u32 q1s = __shfl_xor(pk[t][bs + 1], 32);
        const u32 q2s = __shfl_xor(pk[t][bs + 2], 32);
        const u32 q3s = __shfl_xor(pk[t][bs + 3], 32);
        union { u32 u[4]; bf16x8 v; } pa;
        pa.u[0] = hi ? q2s : pk[t][bs + 0];
        pa.u[1] = hi ? q3s : pk[t][bs + 1];
        pa.u[2] = hi ? pk[t][bs + 2] : q0s;
        pa.u[3] = hi ? pk[t][bs + 3] : q1s;
#pragma unroll
        for (int dt = 0; dt < 4; ++dt) {
          const int d = dt * 32 + l31;
          const bf16x8 vf = *reinterpret_cast<const bf16x8*>(
              &Vt[d * KBLK + (((ks * 2 + hi) ^ ((d >> 2) & 7)) * 8)]);
          oacc[dt] = mfma32(pa.v, vf, oacc[dt]);
        }
      }
      __builtin_amdgcn_s_setprio(0);
    }

    BAR();
  }

  const float li = __builtin_amdgcn_rcpf(lrow);
#pragma unroll
  for (int r = 0; r < 16; ++r) {
    const int rowq = (r & 3) + 8 * (r >> 2) + 4 * hi;
    const float lr = __shfl(li, rowq);
    u16* op = &O[(rowbase + qw + rowq) * DMODEL + hoff + l31];
#pragma unroll
    for (int dt = 0; dt < 4; ++dt) op[dt * 32] = f2bf(oacc[dt][r] * lr);
  }
}

// ---------------- launcher --------------------------------------------
extern "C" void kernel_launch(void* const* d_in, const int* in_sizes, int n_in,
                              void* d_out, int out_size, void* d_ws,
                              size_t ws_size, hipStream_t stream) {
  const int Bv = 2, S = 2048, D = 2048;
  const int M = Bv * S;
  const size_t NT = (size_t)M * D;   // 8388608
  const size_t NW = (size_t)D * D;   // 4194304

  const float* q = (const float*)d_in[0];
  const float* k = (const float*)d_in[1];
  const float* v = (const float*)d_in[2];
  const float* wq_w = (const float*)d_in[4];
  const float* wq_b = (const float*)d_in[5];
  const float* wk_w = (const float*)d_in[6];
  const float* wk_b = (const float*)d_in[7];
  const float* wv_w = (const float*)d_in[8];
  const float* wv_b = (const float*)d_in[9];
  const float* dw = (const float*)d_in[10];
  const float* db = (const float*)d_in[11];
  float* out = (float*)d_out;

  const dim3 blk(256);
  const dim3 gattn(512);
  const size_t need = (7 * NT + 4 * NW) * 2;  // ~151 MB

  if (ws_size >= need) {
    u16* base = (u16*)d_ws;
    u16* Xq = base;
    u16* Xk = Xq + NT;
    u16* Xv = Xk + NT;
    u16* Wq = Xv + NT;
    u16* Wk = Wq + NW;
    u16* Wv = Wk + NW;
    u16* Wd = Wv + NW;
    u16* Qh = Wd + NW;
    u16* Kh = Qh + NT;
    u16* Vh = Kh + NT;
    u16* Obf = Vh + NT;

    conv_all<<<dim3((unsigned)(NT / 1024), 7), blk, 0, stream>>>(
        q, k, v, wq_w, wk_w, wv_w, dw, Xq, Xk, Xv, Wq, Wk, Wv, Wd, NT, NW);
    gemm_qkv3<<<dim3(1536), blk, 0, stream>>>(
        Xq, Xk, Xv, Wq, Wk, Wv, wq_b, wk_b, wv_b, Qh, Kh, Vh);
    flash_attn<<<gattn, blk, 0, stream>>>(Qh, Kh, Vh, Obf);
    gemm_one<<<dim3(512), blk, 0, stream>>>(Obf, Wd, db, out, 1);
  } else {
    u16* Xbf = (u16*)d_ws;
    u16* Wbf = Xbf + NT;
    u16* Qh = Wbf + NW;
    u16* Kh = Qh + NT;
    u16* Vh = Kh + NT;
    u16* Obf = Vh + NT;
    const dim3 gact((unsigned)(NT / 1024));
    const dim3 gw((unsigned)(NW / 1024));

    conv_f32_bf16<<<gact, blk, 0, stream>>>(q, Xbf);
    conv_f32_bf16<<<gw, blk, 0, stream>>>(wq_w, Wbf);
    gemm_one<<<dim3(512), blk, 0, stream>>>(Xbf, Wbf, wq_b, Qh, 0);
    conv_f32_bf16<<<gact, blk, 0, stream>>>(k, Xbf);
    conv_f32_bf16<<<gw, blk, 0, stream>>>(wk_w, Wbf);
    gemm_one<<<dim3(512), blk, 0, stream>>>(Xbf, Wbf, wk_b, Kh, 0);
    conv_f32_bf16<<<gact, blk, 0, stream>>>(v, Xbf);
    conv_f32_bf16<<<gw, blk, 0, stream>>>(wv_w, Wbf);
    gemm_one<<<dim3(512), blk, 0, stream>>>(Xbf, Wbf, wv_b, Vh, 0);
    flash_attn<<<gattn, blk, 0, stream>>>(Qh, Kh, Vh, Obf);
    conv_f32_bf16<<<gw, blk, 0, stream>>>(dw, Wbf);
    gemm_one<<<dim3(512), blk, 0, stream>>>(Obf, Wbf, db, out, 1);
  }
}

// Round 13
// 289.421 us; speedup vs baseline: 1.1166x; 1.0308x over previous
//
#include <hip/hip_runtime.h>
#include <hip/hip_bf16.h>

// GPT3 attention block, B=2 S=2048 D=2048 H=16 Dh=128.
// 4-phase/iter (16 MFMA/phase) 128x128 counted-vmcnt GEMM (2 blocks/CU,
// L2/L3-aware XCD map) + swapped-QK^T 32x32 flash attention.

typedef __bf16 bf16x8 __attribute__((ext_vector_type(8)));
typedef float f32x4 __attribute__((ext_vector_type(4)));
typedef float f32x16 __attribute__((ext_vector_type(16)));
typedef unsigned short u16;
typedef unsigned int u32;

#define DEV static __device__ __forceinline__

DEV void gload_lds16(const void* g, void* l) {
  __builtin_amdgcn_global_load_lds(
      (const __attribute__((address_space(1))) void*)g,
      (__attribute__((address_space(3))) void*)l, 16, 0, 0);
}

DEV f32x4 mfma16(bf16x8 a, bf16x8 b, f32x4 c) {
  return __builtin_amdgcn_mfma_f32_16x16x32_bf16(a, b, c, 0, 0, 0);
}

DEV f32x16 mfma32(bf16x8 a, bf16x8 b, f32x16 c) {
  return __builtin_amdgcn_mfma_f32_32x32x16_bf16(a, b, c, 0, 0, 0);
}

DEV u16 f2bf(float x) {
  return __builtin_bit_cast(u16, __float2bfloat16(x));
}

DEV u32 pack2(float lo, float hi_) {
  return (u32)f2bf(lo) | ((u32)f2bf(hi_) << 16);
}

#define BAR() __builtin_amdgcn_s_barrier()

// ---------------- fp32 -> bf16 conversion ----------------------------
__global__ void __launch_bounds__(256) conv_f32_bf16(
    const float* __restrict__ in, u16* __restrict__ out) {
  const size_t i = ((size_t)blockIdx.x * 256 + threadIdx.x) * 4;
  const float4 v = *reinterpret_cast<const float4*>(in + i);
  ushort4 o;
  o.x = f2bf(v.x); o.y = f2bf(v.y); o.z = f2bf(v.z); o.w = f2bf(v.w);
  *reinterpret_cast<ushort4*>(out + i) = o;
}

__global__ void __launch_bounds__(256) conv_all(
    const float* __restrict__ s0, const float* __restrict__ s1,
    const float* __restrict__ s2, const float* __restrict__ s3,
    const float* __restrict__ s4, const float* __restrict__ s5,
    const float* __restrict__ s6,
    u16* __restrict__ d0, u16* __restrict__ d1, u16* __restrict__ d2,
    u16* __restrict__ d3, u16* __restrict__ d4, u16* __restrict__ d5,
    u16* __restrict__ d6, const size_t nact, const size_t nw) {
  const int j = blockIdx.y;
  const size_t i = ((size_t)blockIdx.x * 256 + threadIdx.x) * 4;
  const float* s; u16* d; size_t n;
  switch (j) {
    case 0: s = s0; d = d0; n = nact; break;
    case 1: s = s1; d = d1; n = nact; break;
    case 2: s = s2; d = d2; n = nact; break;
    case 3: s = s3; d = d3; n = nw; break;
    case 4: s = s4; d = d4; n = nw; break;
    case 5: s = s5; d = d5; n = nw; break;
    default: s = s6; d = d6; n = nw; break;
  }
  if (i >= n) return;
  const float4 v = *reinterpret_cast<const float4*>(s + i);
  ushort4 o;
  o.x = f2bf(v.x); o.y = f2bf(v.y); o.z = f2bf(v.z); o.w = f2bf(v.w);
  *reinterpret_cast<ushort4*>(d + i) = o;
}

// ---------------- 4-phase 128x128 GEMM: C = A @ B^T + bias ------------
// K=2048, BK=64 (32 K-tiles, 16 iters x 2 tiles). 256 threads = 4 waves
// (2M x 2N), per-wave C = 64x64 = acc[4][4]. LDS 64 KB -> 2 blocks/CU.
// r13 restructure: 4 phases/iter with 16 MFMA between each barrier pair
// (was 8 -> phase fixed costs halved; B frags read once per K-tile).
//   ph0: read A-rows0-31 + B-all of tile T  | stage A(T+1)        | 16 MFMA
//   ph1: read A-rows32-63 (B in regs)       | stage B(T+2), w(4)  | 16 MFMA
//   ph2: read A-rows0-31 + B-all of tile T+1| stage A(T+2)        | 16 MFMA
//   ph3: read A-rows32-63                   | stage B(T+3), w(4)  | 16 MFMA
// Ledger (4-load groups, issue order): prologue B(0),A(0),B(1),vmcnt(4).
// At ph1-end in-flight {B(T+1),A(T+1),B(T+2)}=12 -> vmcnt(4) retires
// B(T+1)+A(T+1) BEFORE ph2 reads tile T+1. At ph3-end in-flight
// {B(T+2),A(T+2),B(T+3)}=12 -> vmcnt(4) retires tile T+2 before next
// iter ph0. WAR: each staged buffer >=1 barrier past its last ds_read.
// Tail iter: stages only A(31); vmcnt(0) at ph1/ph3.
#define GK 2048

DEV void gemm128_core(const u16* __restrict__ A, const u16* __restrict__ Bw,
                      const float* __restrict__ bias, void* __restrict__ Cout,
                      const int m0, const int n0, const int N,
                      const int out_f32, u16* AsB, u16* BsB) {
  const int tid = threadIdx.x;
  const int lane = tid & 63;
  const int wid = tid >> 6;
  const int wr = wid >> 1, wc = wid & 1;
  const int g = lane >> 4;
  const int r16 = lane & 15;

  int offA[2], offB[2], dstE[2];
#pragma unroll
  for (int rr = 0; rr < 2; ++rr) {
    const int G = rr * 256 + tid;
    const int rp = G >> 3;
    const int s = (G & 7) ^ (rp & 7);
    const int row = rp * 2 + (s >> 2);
    const int ch = s & 3;
    offA[rr] = (m0 + row) * GK + ch * 8;
    offB[rr] = (n0 + row) * GK + ch * 8;
    dstE[rr] = rr * 2048 + wid * 512;
  }

#define STAGE_A(kt, kh) do {                                              \
    u16* base_ = AsB + (((kt) & 1) * 2 + (kh)) * 4096;                    \
    const int go_ = (kt) * 64 + (kh) * 32;                                \
    gload_lds16(A + (size_t)(offA[0] + go_), base_ + dstE[0]);            \
    gload_lds16(A + (size_t)(offA[1] + go_), base_ + dstE[1]);            \
  } while (0)
#define STAGE_B(kt, kh) do {                                              \
    u16* base_ = BsB + (((kt) & 1) * 2 + (kh)) * 4096;                    \
    const int go_ = (kt) * 64 + (kh) * 32;                                \
    gload_lds16(Bw + (size_t)(offB[0] + go_), base_ + dstE[0]);           \
    gload_lds16(Bw + (size_t)(offB[1] + go_), base_ + dstE[1]);           \
  } while (0)
// read A-frag rows for half MH (2 frags x 2 k-subtiles) of buffer `buf`
#define READ_A2(MH, buf) do {                                             \
    _Pragma("unroll") for (int i_ = 0; i_ < 2; ++i_) {                    \
      const int row_ = wr * 64 + ((MH) * 2 + i_) * 16 + r16;              \
      const int rp_ = row_ >> 1;                                          \
      const int sl_ = (((row_ & 1) << 2) | g) ^ (rp_ & 7);                \
      const int off_ = rp_ * 64 + sl_ * 8;                                \
      af[i_][0] = *(const bf16x8*)(AsB + ((buf) * 2 + 0) * 4096 + off_);  \
      af[i_][1] = *(const bf16x8*)(AsB + ((buf) * 2 + 1) * 4096 + off_);  \
    } } while (0)
// read ALL B-frags (4 x 2 k-subtiles) of buffer `buf`
#define READ_B4(buf) do {                                                 \
    _Pragma("unroll") for (int j_ = 0; j_ < 4; ++j_) {                    \
      const int row_ = wc * 64 + j_ * 16 + r16;                           \
      const int rp_ = row_ >> 1;                                          \
      const int sl_ = (((row_ & 1) << 2) | g) ^ (rp_ & 7);                \
      const int off_ = rp_ * 64 + sl_ * 8;                                \
      bf[j_][0] = *(const bf16x8*)(BsB + ((buf) * 2 + 0) * 4096 + off_);  \
      bf[j_][1] = *(const bf16x8*)(BsB + ((buf) * 2 + 1) * 4096 + off_);  \
    } } while (0)
// 16 MFMA: A-half MH (af) x all B (bf) x 2 k-subtiles
#define MFMA16(MH) do {                                                   \
    __builtin_amdgcn_s_setprio(1);                                        \
    _Pragma("unroll") for (int i_ = 0; i_ < 2; ++i_)                      \
    _Pragma("unroll") for (int j_ = 0; j_ < 4; ++j_) {                    \
      f32x4 c_ = acc[(MH) * 2 + i_][j_];                                  \
      c_ = mfma16(af[i_][0], bf[j_][0], c_);                              \
      c_ = mfma16(af[i_][1], bf[j_][1], c_);                              \
      acc[(MH) * 2 + i_][j_] = c_;                                        \
    }                                                                     \
    __builtin_amdgcn_s_setprio(0);                                        \
  } while (0)

  f32x4 acc[4][4];
#pragma unroll
  for (int i = 0; i < 4; ++i)
#pragma unroll
    for (int j = 0; j < 4; ++j) acc[i][j] = {0.f, 0.f, 0.f, 0.f};

  bf16x8 af[2][2], bf[4][2];

  // prologue: B(0), A(0), B(1); vmcnt(4) retires B(0)+A(0)
  STAGE_B(0, 0); STAGE_B(0, 1); STAGE_A(0, 0); STAGE_A(0, 1);
  STAGE_B(1, 0); STAGE_B(1, 1);
  asm volatile("s_waitcnt vmcnt(4)" ::: "memory");
  BAR();

  for (int it = 0; it < 16; ++it) {
    const bool tail = (it == 15);
    const int T = 2 * it;
    const int b0 = T & 1, b1 = (T + 1) & 1;  // 0, 1
    // ph0: tile T
    READ_A2(0, b0); READ_B4(b0);
    STAGE_A(T + 1, 0); STAGE_A(T + 1, 1);
    BAR(); MFMA16(0); BAR();
    // ph1
    READ_A2(1, b0);
    if (!tail) {
      STAGE_B(T + 2, 0); STAGE_B(T + 2, 1);
      asm volatile("s_waitcnt vmcnt(4)" ::: "memory");  // tile T+1 landed
    } else {
      asm volatile("s_waitcnt vmcnt(0)" ::: "memory");
    }
    BAR(); MFMA16(1); BAR();
    // ph2: tile T+1
    READ_A2(0, b1); READ_B4(b1);
    if (!tail) { STAGE_A(T + 2, 0); STAGE_A(T + 2, 1); }
    BAR(); MFMA16(0); BAR();
    // ph3
    READ_A2(1, b1);
    if (!tail) {
      STAGE_B(T + 3, 0); STAGE_B(T + 3, 1);
      asm volatile("s_waitcnt vmcnt(4)" ::: "memory");  // tile T+2 landed
    } else {
      asm volatile("s_waitcnt vmcnt(0)" ::: "memory");
    }
    BAR(); MFMA16(1); BAR();
  }

  // epilogue: C/D layout col=lane&15, row=(lane>>4)*4+reg
  const int rbase = m0 + wr * 64 + g * 4;
  const int cb = n0 + wc * 64 + r16;
#pragma unroll
  for (int i = 0; i < 4; ++i) {
#pragma unroll
    for (int j = 0; j < 4; ++j) {
      const int c = cb + j * 16;
      const float bv = bias[c];
#pragma unroll
      for (int r = 0; r < 4; ++r) {
        const float v = acc[i][j][r] + bv;
        const size_t idx = (size_t)(rbase + i * 16 + r) * N + c;
        if (out_f32) ((float*)Cout)[idx] = v;
        else ((u16*)Cout)[idx] = f2bf(v);
      }
    }
  }
#undef STAGE_A
#undef STAGE_B
#undef READ_A2
#undef READ_B4
#undef MFMA16
}

// L2/L3-aware XCD map (r12, FETCH 306->123 MB): per XCD 4 m-panels x 16 n,
// n fast; A-slab 2 MB L2-resident, B L3-resident.
__global__ void __launch_bounds__(256, 2) gemm_qkv3(
    const u16* __restrict__ A0, const u16* __restrict__ A1,
    const u16* __restrict__ A2, const u16* __restrict__ W0,
    const u16* __restrict__ W1, const u16* __restrict__ W2,
    const float* __restrict__ b0, const float* __restrict__ b1,
    const float* __restrict__ b2, u16* __restrict__ C0,
    u16* __restrict__ C1, u16* __restrict__ C2) {
  __shared__ u16 AsB[4 * 4096];  // 32 KB
  __shared__ u16 BsB[4 * 4096];  // 32 KB
  const int xcd = blockIdx.x & 7;
  const int t = blockIdx.x >> 3;      // 0..191
  const int which = t >> 6;           // 0..2
  const int r = t & 63;
  const int m0 = (xcd * 4 + (r >> 4)) << 7;
  const int n0 = (r & 15) << 7;
  const u16* A = which == 0 ? A0 : which == 1 ? A1 : A2;
  const u16* W = which == 0 ? W0 : which == 1 ? W1 : W2;
  const float* bb = which == 0 ? b0 : which == 1 ? b1 : b2;
  u16* C = which == 0 ? C0 : which == 1 ? C1 : C2;
  gemm128_core(A, W, bb, C, m0, n0, 2048, 0, AsB, BsB);
}

__global__ void __launch_bounds__(256, 2) gemm_one(
    const u16* __restrict__ A, const u16* __restrict__ Bw,
    const float* __restrict__ bias, void* __restrict__ Cout,
    const int out_f32) {
  __shared__ u16 AsB[4 * 4096];
  __shared__ u16 BsB[4 * 4096];
  const int xcd = blockIdx.x & 7;
  const int t = blockIdx.x >> 3;      // 0..63
  const int m0 = (xcd * 4 + (t >> 4)) << 7;
  const int n0 = (t & 15) << 7;
  gemm128_core(A, Bw, bias, Cout, m0, n0, 2048, out_f32, AsB, BsB);
}

// ---------------- causal flash attention (swapped QK^T, 32x32) --------
#define SEQ 2048
#define DMODEL 2048
#define DH 128
#define QBLK 128
#define KBLK 64
#define C1 0.12751744f   // (1/sqrt(128)) * log2(e)
#define THR_RAW 62.73f   // defer-max threshold: 8 / C1

__global__ void __launch_bounds__(256, 2) flash_attn(
    const u16* __restrict__ Qh, const u16* __restrict__ Kh,
    const u16* __restrict__ Vh, u16* __restrict__ O) {
  __shared__ u16 Ks[2][KBLK * DH];  // 32 KB
  __shared__ u16 Vt[DH * KBLK];     // 16 KB

  const int tid = threadIdx.x;
  const int lane = tid & 63;
  const int w = tid >> 6;
  const int hi = lane >> 5;
  const int l31 = lane & 31;

  const int cc = blockIdx.x;
  const int low = cc & 15;
  const int bh = (cc >> 4) & 31;
  const int h = bh & 15;
  const int b = bh >> 4;
  const int g0 = low ^ h;
  const int qt = b ? (15 - g0) : g0;
  const int q0 = qt * QBLK;
  const size_t rowbase = (size_t)b * SEQ;
  const int hoff = h * DH;
  const int qw = q0 + w * 32;
  const int qlane = qw + l31;

  bf16x8 aq[8];
  {
    const u16* qp = &Qh[(rowbase + qlane) * DMODEL + hoff + hi * 8];
#pragma unroll
    for (int c = 0; c < 8; ++c)
      aq[c] = *reinterpret_cast<const bf16x8*>(qp + c * 16);
  }

  f32x16 oacc[4];
#pragma unroll
  for (int dt = 0; dt < 4; ++dt)
#pragma unroll
    for (int r = 0; r < 16; ++r) oacc[dt][r] = 0.f;
  float mrow = -1e30f, lrow = 0.f;

  const int krl = w * 16 + (lane >> 4);
  const int kg4 = w * 4 + (lane >> 4);
  const int du = lane & 15;

  const int nkt = 2 * qt + 2;
  const int ktd = qw >> 6;

  auto stageK = [&](int kt) {
#pragma unroll
    for (int i = 0; i < 4; ++i) {
      const int r = krl + i * 4;
      const int cg = (lane & 15) ^ (r & 15);
      gload_lds16(&Kh[(rowbase + kt * KBLK + r) * DMODEL + hoff + cg * 8],
                  &Ks[kt & 1][(w * 16 + i * 4) * DH]);
    }
  };

  stageK(0);
  uint4 vv[4];
#pragma unroll
  for (int r = 0; r < 4; ++r)
    vv[r] = *reinterpret_cast<const uint4*>(
        &Vh[(rowbase + kg4 * 4 + r) * DMODEL + hoff + du * 8]);

  for (int kt = 0; kt < nkt; ++kt) {
    const int k0 = kt * KBLK;
    if (kt + 1 < nkt) {
      stageK(kt + 1);
      asm volatile("s_waitcnt vmcnt(4)" ::: "memory");
    } else {
      asm volatile("s_waitcnt vmcnt(0)" ::: "memory");
    }

#pragma unroll
    for (int j = 0; j < 8; ++j) {
      const int d = du * 8 + j;
      ushort4 pk4;
      pk4.x = ((const u16*)&vv[0])[j];
      pk4.y = ((const u16*)&vv[1])[j];
      pk4.z = ((const u16*)&vv[2])[j];
      pk4.w = ((const u16*)&vv[3])[j];
      const int slot = (((kg4 >> 1) ^ ((d >> 2) & 7)) * 8) + (kg4 & 1) * 4;
      *reinterpret_cast<ushort4*>(&Vt[d * KBLK + slot]) = pk4;
    }
    asm volatile("s_waitcnt lgkmcnt(0)" ::: "memory");
    BAR();

    const bool active = (kt <= ktd);
    const u16* kb = &Ks[kt & 1][0];
    float p[2][16];
    bool act1 = false;

    if (active) {
      const bool diag = (kt == ktd);
      act1 = (kt < ktd) || (w & 1);
      const bool m0q = diag && !(w & 1);
      const bool m1q = diag && (w & 1);
      {
        f32x16 s;
#pragma unroll
        for (int r = 0; r < 16; ++r) s[r] = 0.f;
        __builtin_amdgcn_s_setprio(1);
#pragma unroll
        for (int c = 0; c < 8; ++c) {
          const int row = l31;
          const bf16x8 kf = *reinterpret_cast<const bf16x8*>(
              &kb[row * DH + (((c * 2 + hi) ^ (row & 15)) * 8)]);
          s = mfma32(kf, aq[c], s);
        }
        __builtin_amdgcn_s_setprio(0);
#pragma unroll
        for (int r = 0; r < 16; ++r) {
          const int krow = (r & 3) + 8 * (r >> 2) + 4 * hi;
          p[0][r] = (m0q && (k0 + krow > qlane)) ? -1e9f : s[r];
        }
      }
      if (act1) {
        f32x16 s;
#pragma unroll
        for (int r = 0; r < 16; ++r) s[r] = 0.f;
        __builtin_amdgcn_s_setprio(1);
#pragma unroll
        for (int c = 0; c < 8; ++c) {
          const int row = 32 + l31;
          const bf16x8 kf = *reinterpret_cast<const bf16x8*>(
              &kb[row * DH + (((c * 2 + hi) ^ (row & 15)) * 8)]);
          s = mfma32(kf, aq[c], s);
        }
        __builtin_amdgcn_s_setprio(0);
#pragma unroll
        for (int r = 0; r < 16; ++r) {
          const int krow = (r & 3) + 8 * (r >> 2) + 4 * hi;
          p[1][r] = (m1q && (k0 + 32 + krow > qlane)) ? -1e9f : s[r];
        }
      } else {
#pragma unroll
        for (int r = 0; r < 16; ++r) p[1][r] = -1e9f;
      }
    }

    if (kt + 1 < nkt) {
#pragma unroll
      for (int r = 0; r < 4; ++r)
        vv[r] = *reinterpret_cast<const uint4*>(
            &Vh[(rowbase + k0 + KBLK + kg4 * 4 + r) * DMODEL + hoff + du * 8]);
    }

    if (active) {
      float mx0 = fmaxf(p[0][0], p[1][0]);
      float mx1 = fmaxf(p[0][1], p[1][1]);
      float mx2 = fmaxf(p[0][2], p[1][2]);
      float mx3 = fmaxf(p[0][3], p[1][3]);
#pragma unroll
      for (int r = 4; r < 16; r += 4) {
        mx0 = fmaxf(mx0, fmaxf(p[0][r + 0], p[1][r + 0]));
        mx1 = fmaxf(mx1, fmaxf(p[0][r + 1], p[1][r + 1]));
        mx2 = fmaxf(mx2, fmaxf(p[0][r + 2], p[1][r + 2]));
        mx3 = fmaxf(mx3, fmaxf(p[0][r + 3], p[1][r + 3]));
      }
      float mx = fmaxf(fmaxf(mx0, mx1), fmaxf(mx2, mx3));
      mx = fmaxf(mx, __shfl_xor(mx, 32));

      const bool need = (mx > mrow + THR_RAW);
      if (__any((int)need)) {
        const float mn = fmaxf(mrow, mx);
        const float al = exp2f((mrow - mn) * C1);
        mrow = mn;
        lrow *= al;
#pragma unroll
        for (int r = 0; r < 16; ++r) {
          const float ar = __shfl(al, (r & 3) + 8 * (r >> 2) + 4 * hi);
#pragma unroll
          for (int dt = 0; dt < 4; ++dt) oacc[dt][r] *= ar;
        }
      }

      float s0 = 0.f, s1 = 0.f, s2 = 0.f, s3 = 0.f;
#pragma unroll
      for (int t = 0; t < 2; ++t)
#pragma unroll
        for (int r = 0; r < 16; r += 4) {
          p[t][r + 0] = exp2f((p[t][r + 0] - mrow) * C1);
          p[t][r + 1] = exp2f((p[t][r + 1] - mrow) * C1);
          p[t][r + 2] = exp2f((p[t][r + 2] - mrow) * C1);
          p[t][r + 3] = exp2f((p[t][r + 3] - mrow) * C1);
          s0 += p[t][r + 0]; s1 += p[t][r + 1];
          s2 += p[t][r + 2]; s3 += p[t][r + 3];
        }
      float sum = (s0 + s1) + (s2 + s3);
      sum += __shfl_xor(sum, 32);
      lrow += sum;

      u32 pk[2][8];
#pragma unroll
      for (int t = 0; t < 2; ++t)
#pragma unroll
        for (int m = 0; m < 8; ++m)
          pk[t][m] = pack2(p[t][2 * m], p[t][2 * m + 1]);

      __builtin_amdgcn_s_setprio(1);
#pragma unroll
      for (int ks = 0; ks < 4; ++ks) {
        if (ks >= 2 && !act1) break;
        const int t = ks >> 1;
        const int bs = (ks & 1) * 4;
        const u32 q0s = __shfl_xor(pk[t][bs + 0], 32);
        const u32 q1s = __shfl_xor(pk[t][bs + 1], 32);
        const u32 q2s = __shfl_xor(pk[t][bs + 2], 32);
        const u32 q3s = __shfl_xor(pk[t][bs + 3], 32);
        union { u32 u[4]; bf16x8 v; } pa;
        pa.u[0] = hi ? q2s : pk[t][bs + 0];
        pa.u[1] = hi ? q3s : pk[t][bs + 1];
        pa.u[2] = hi ? pk[t][bs + 2] : q0s;
        pa.u[3] = hi ? pk[t][bs + 3] : q1s;
#pragma unroll
        for (int dt = 0; dt < 4; ++dt) {
          const int d = dt * 32 + l31;
          const bf16x8 vf = *reinterpret_cast<const bf16x8*>(
              &Vt[d * KBLK + (((ks * 2 + hi) ^ ((d >> 2) & 7)) * 8)]);
          oacc[dt] = mfma32(pa.v, vf, oacc[dt]);
        }
      }
      __builtin_amdgcn_s_setprio(0);
    }

    BAR();
  }

  const float li = __builtin_amdgcn_rcpf(lrow);
#pragma unroll
  for (int r = 0; r < 16; ++r) {
    const int rowq = (r & 3) + 8 * (r >> 2) + 4 * hi;
    const float lr = __shfl(li, rowq);
    u16* op = &O[(rowbase + qw + rowq) * DMODEL + hoff + l31];
#pragma unroll
    for (int dt = 0; dt < 4; ++dt) op[dt * 32] = f2bf(oacc[dt][r] * lr);
  }
}

// ---------------- launcher --------------------------------------------
extern "C" void kernel_launch(void* const* d_in, const int* in_sizes, int n_in,
                              void* d_out, int out_size, void* d_ws,
                              size_t ws_size, hipStream_t stream) {
  const int Bv = 2, S = 2048, D = 2048;
  const int M = Bv * S;
  const size_t NT = (size_t)M * D;   // 8388608
  const size_t NW = (size_t)D * D;   // 4194304

  const float* q = (const float*)d_in[0];
  const float* k = (const float*)d_in[1];
  const float* v = (const float*)d_in[2];
  const float* wq_w = (const float*)d_in[4];
  const float* wq_b = (const float*)d_in[5];
  const float* wk_w = (const float*)d_in[6];
  const float* wk_b = (const float*)d_in[7];
  const float* wv_w = (const float*)d_in[8];
  const float* wv_b = (const float*)d_in[9];
  const float* dw = (const float*)d_in[10];
  const float* db = (const float*)d_in[11];
  float* out = (float*)d_out;

  const dim3 blk(256);
  const dim3 gattn(512);
  const size_t need = (7 * NT + 4 * NW) * 2;  // ~151 MB

  if (ws_size >= need) {
    u16* base = (u16*)d_ws;
    u16* Xq = base;
    u16* Xk = Xq + NT;
    u16* Xv = Xk + NT;
    u16* Wq = Xv + NT;
    u16* Wk = Wq + NW;
    u16* Wv = Wk + NW;
    u16* Wd = Wv + NW;
    u16* Qh = Wd + NW;
    u16* Kh = Qh + NT;
    u16* Vh = Kh + NT;
    u16* Obf = Vh + NT;

    conv_all<<<dim3((unsigned)(NT / 1024), 7), blk, 0, stream>>>(
        q, k, v, wq_w, wk_w, wv_w, dw, Xq, Xk, Xv, Wq, Wk, Wv, Wd, NT, NW);
    gemm_qkv3<<<dim3(1536), blk, 0, stream>>>(
        Xq, Xk, Xv, Wq, Wk, Wv, wq_b, wk_b, wv_b, Qh, Kh, Vh);
    flash_attn<<<gattn, blk, 0, stream>>>(Qh, Kh, Vh, Obf);
    gemm_one<<<dim3(512), blk, 0, stream>>>(Obf, Wd, db, out, 1);
  } else {
    u16* Xbf = (u16*)d_ws;
    u16* Wbf = Xbf + NT;
    u16* Qh = Wbf + NW;
    u16* Kh = Qh + NT;
    u16* Vh = Kh + NT;
    u16* Obf = Vh + NT;
    const dim3 gact((unsigned)(NT / 1024));
    const dim3 gw((unsigned)(NW / 1024));

    conv_f32_bf16<<<gact, blk, 0, stream>>>(q, Xbf);
    conv_f32_bf16<<<gw, blk, 0, stream>>>(wq_w, Wbf);
    gemm_one<<<dim3(512), blk, 0, stream>>>(Xbf, Wbf, wq_b, Qh, 0);
    conv_f32_bf16<<<gact, blk, 0, stream>>>(k, Xbf);
    conv_f32_bf16<<<gw, blk, 0, stream>>>(wk_w, Wbf);
    gemm_one<<<dim3(512), blk, 0, stream>>>(Xbf, Wbf, wk_b, Kh, 0);
    conv_f32_bf16<<<gact, blk, 0, stream>>>(v, Xbf);
    conv_f32_bf16<<<gw, blk, 0, stream>>>(wv_w, Wbf);
    gemm_one<<<dim3(512), blk, 0, stream>>>(Xbf, Wbf, wv_b, Vh, 0);
    flash_attn<<<gattn, blk, 0, stream>>>(Qh, Kh, Vh, Obf);
    conv_f32_bf16<<<gw, blk, 0, stream>>>(dw, Wbf);
    gemm_one<<<dim3(512), blk, 0, stream>>>(Obf, Wbf, db, out, 1);
  }
}